// Round 1
// baseline (1672.038 us; speedup 1.0000x reference)
//
#include <hip/hip_runtime.h>
#include <math.h>

#define CD    128
#define HIDD  64
#define HFD   32
#define WFD   88
#define TILE  64
#define NTHR  256

// ---------------------------------------------------------------------------
// Kernel 1: invert B 4x4 lidar-aug matrices (double-precision Gauss-Jordan)
// ---------------------------------------------------------------------------
__global__ void prep_inv_kernel(const float* __restrict__ aug,
                                float* __restrict__ auginv, int B) {
  int b = threadIdx.x;
  if (b >= B) return;
  double m[4][8];
  for (int i = 0; i < 4; ++i)
    for (int j = 0; j < 4; ++j) {
      m[i][j]     = (double)aug[b * 16 + i * 4 + j];
      m[i][4 + j] = (i == j) ? 1.0 : 0.0;
    }
  for (int col = 0; col < 4; ++col) {
    int piv = col;
    double best = fabs(m[col][col]);
    for (int r = col + 1; r < 4; ++r) {
      double v = fabs(m[r][col]);
      if (v > best) { best = v; piv = r; }
    }
    if (piv != col)
      for (int j = 0; j < 8; ++j) {
        double t = m[col][j]; m[col][j] = m[piv][j]; m[piv][j] = t;
      }
    double f = 1.0 / m[col][col];
    for (int j = 0; j < 8; ++j) m[col][j] *= f;
    for (int r = 0; r < 4; ++r)
      if (r != col) {
        double g = m[r][col];
        for (int j = 0; j < 8; ++j) m[r][j] -= g * m[col][j];
      }
  }
  for (int i = 0; i < 4; ++i)
    for (int j = 0; j < 4; ++j)
      auginv[b * 16 + i * 4 + j] = (float)m[i][4 + j];
}

// ---------------------------------------------------------------------------
// Kernel 2: transpose img_feats (B,C,H,W) -> (B,H,W,C) for coalesced gather
// ---------------------------------------------------------------------------
__global__ void transpose_img_kernel(const float* __restrict__ img,
                                     float* __restrict__ imgT, int total) {
  int o = blockIdx.x * blockDim.x + threadIdx.x;
  if (o >= total) return;
  int c   = o & (CD - 1);
  int pos = o >> 7;          // (b*HF + y)*WF + x
  int xw  = pos % WFD;
  int tmp = pos / WFD;       // b*HF + y
  int yh  = tmp & (HFD - 1);
  int b   = tmp >> 5;
  imgT[o] = img[((b * CD + c) * HFD + yh) * WFD + xw];
}

__device__ __forceinline__ void fma4(float* acc, float s, const float4 w) {
  acc[0] = fmaf(s, w.x, acc[0]);
  acc[1] = fmaf(s, w.y, acc[1]);
  acc[2] = fmaf(s, w.z, acc[2]);
  acc[3] = fmaf(s, w.w, acc[3]);
}

// per-point epilogue: LN + gain, 8 lanes own one point (16 ch each)
__device__ __forceinline__ void epilogue_point(
    const float* __restrict__ sh, const float* da, int p, int n, int N,
    int c0, int cg, const float* __restrict__ lng,
    const float* __restrict__ lnb, float* __restrict__ out, size_t OFF_GAIN) {
  const int rb  = p * 256;
  const int key = (p & 7) << 2;
  float xr[16];
  float sd = 0.0f, sx = 0.0f, sr = 0.0f, sr2 = 0.0f;
#pragma unroll
  for (int i = 0; i < 16; i += 4) {
    const float4 xv = *reinterpret_cast<const float4*>(&sh[rb + ((c0 + i) ^ key)]);
    const float xs0 = xv.x, xs1 = xv.y, xs2 = xv.z, xs3 = xv.w;
    float d, r;
    d = da[i];     r = xs0 + d; xr[i]     = r; sd += d * d; sx += xs0 * xs0; sr += r; sr2 += r * r;
    d = da[i + 1]; r = xs1 + d; xr[i + 1] = r; sd += d * d; sx += xs1 * xs1; sr += r; sr2 += r * r;
    d = da[i + 2]; r = xs2 + d; xr[i + 2] = r; sd += d * d; sx += xs2 * xs2; sr += r; sr2 += r * r;
    d = da[i + 3]; r = xs3 + d; xr[i + 3] = r; sd += d * d; sx += xs3 * xs3; sr += r; sr2 += r * r;
  }
#pragma unroll
  for (int m = 1; m < 8; m <<= 1) {
    sd  += __shfl_xor(sd, m);
    sx  += __shfl_xor(sx, m);
    sr  += __shfl_xor(sr, m);
    sr2 += __shfl_xor(sr2, m);
  }
  const float mu   = sr * (1.0f / 128.0f);
  const float var  = sr2 * (1.0f / 128.0f) - mu * mu;
  const float rstd = rsqrtf(var + 1e-5f);
  if (n < N) {
    if (cg == 0) {
      const float g = sqrtf(sd) / (sqrtf(sx) + 1e-6f);
      out[OFF_GAIN + n] = fminf(fmaxf(1.0f - expf(-g), 0.0f), 1.0f);
    }
#pragma unroll
    for (int i = 0; i < 16; i += 4) {
      const float4 gv = *reinterpret_cast<const float4*>(lng + c0 + i);
      const float4 bv = *reinterpret_cast<const float4*>(lnb + c0 + i);
      float4 o;
      o.x = (xr[i]     - mu) * rstd * gv.x + bv.x;
      o.y = (xr[i + 1] - mu) * rstd * gv.y + bv.y;
      o.z = (xr[i + 2] - mu) * rstd * gv.z + bv.z;
      o.w = (xr[i + 3] - mu) * rstd * gv.w + bv.w;
      *reinterpret_cast<float4*>(&out[(size_t)n * CD + c0 + i]) = o;
    }
  }
}

// ---------------------------------------------------------------------------
// Main fused kernel: 64 points / block, 256 threads
// LDS: sh[64][256] = [x | sampled] per point, XOR-swizzled (col ^ ((row&7)<<2))
// ---------------------------------------------------------------------------
__global__ __launch_bounds__(NTHR)
void fused_kernel(const float* __restrict__ x,
                  const int* __restrict__ indices,
                  const float* __restrict__ voxel_size,
                  const float* __restrict__ pc_range,
                  const float* __restrict__ trans,
                  const float* __restrict__ auginv,
                  const float* __restrict__ imgT,
                  const float* __restrict__ W1, const float* __restrict__ b1,
                  const float* __restrict__ W2, const float* __restrict__ b2,
                  const float* __restrict__ We1, const float* __restrict__ be1,
                  const float* __restrict__ We2, const float* __restrict__ be2,
                  const float* __restrict__ lng, const float* __restrict__ lnb,
                  const int* __restrict__ img_h_p, const int* __restrict__ img_w_p,
                  float* __restrict__ out, int N) {
  __shared__ float sh[TILE * 256];   // 64 KB exactly
  const int tid  = threadIdx.x;
  const int base = blockIdx.x * TILE;
  const size_t NN       = (size_t)N;
  const size_t OFF_PFG  = NN * CD;
  const size_t OFF_GAIN = OFF_PFG + NN;
  const size_t OFF_RN   = OFF_GAIN + NN;
  const size_t OFF_VAL  = OFF_RN + NN;

  const float vsx = voxel_size[0] * 8.0f;
  const float vsy = voxel_size[1] * 8.0f;
  const float vsz = voxel_size[2] * 8.0f;
  const float pcx = pc_range[0], pcy = pc_range[1], pcz = pc_range[2];
  const float su  = (float)WFD / (float)(*img_w_p);
  const float sv  = (float)HFD / (float)(*img_h_p);

  // ---- phase 1: geometry + gather + stage x and sampled into LDS ----
  for (int pp = 0; pp < TILE / 2; ++pp) {
    const int p = pp * 2 + (tid >> 7);
    const int n = base + p;
    const int c = tid & (CD - 1);
    float xval = 0.0f, sval = 0.0f;
    if (n < N) {
      const int4 idx = *reinterpret_cast<const int4*>(indices + (size_t)n * 4);
      const int b = idx.x;
      const float cx = (float)idx.w * vsx + pcx + 0.5f * vsx;
      const float cy = (float)idx.z * vsy + pcy + 0.5f * vsy;
      const float cz = (float)idx.y * vsz + pcz + 0.5f * vsz;
      const float4 A0 = *reinterpret_cast<const float4*>(auginv + b * 16 + 0);
      const float4 A1 = *reinterpret_cast<const float4*>(auginv + b * 16 + 4);
      const float4 A2 = *reinterpret_cast<const float4*>(auginv + b * 16 + 8);
      const float4 A3 = *reinterpret_cast<const float4*>(auginv + b * 16 + 12);
      const float h0 = A0.x * cx + A0.y * cy + A0.z * cz + A0.w;
      const float h1 = A1.x * cx + A1.y * cy + A1.z * cz + A1.w;
      const float h2 = A2.x * cx + A2.y * cy + A2.z * cz + A2.w;
      const float h3 = A3.x * cx + A3.y * cy + A3.z * cz + A3.w;
      const float4 T0 = *reinterpret_cast<const float4*>(trans + b * 12 + 0);
      const float4 T1 = *reinterpret_cast<const float4*>(trans + b * 12 + 4);
      const float4 T2 = *reinterpret_cast<const float4*>(trans + b * 12 + 8);
      const float q0    = T0.x * h0 + T0.y * h1 + T0.z * h2 + T0.w * h3;
      const float q1    = T1.x * h0 + T1.y * h1 + T1.z * h2 + T1.w * h3;
      const float depth = T2.x * h0 + T2.y * h1 + T2.z * h2 + T2.w * h3;
      const float safe = fmaxf(depth, 1e-5f);
      const float u = q0 / safe, v = q1 / safe;
      const float un = 2.0f * (u * su) / 87.0f - 1.0f;
      const float vn = 2.0f * (v * sv) / 31.0f - 1.0f;
      const float validf =
          (depth > 1e-5f && fabsf(un) <= 1.0f && fabsf(vn) <= 1.0f) ? 1.0f : 0.0f;
      const float xp  = (un + 1.0f) * 0.5f * 87.0f;
      const float yp  = (vn + 1.0f) * 0.5f * 31.0f;
      const float x0f = floorf(xp), y0f = floorf(yp);
      const float wx1 = xp - x0f, wy1 = yp - y0f;
      const float wx0 = 1.0f - wx1, wy0 = 1.0f - wy1;
      const bool okx0 = (x0f >= 0.0f) && (x0f <= 87.0f);
      const bool okx1 = (x0f + 1.0f >= 0.0f) && (x0f + 1.0f <= 87.0f);
      const bool oky0 = (y0f >= 0.0f) && (y0f <= 31.0f);
      const bool oky1 = (y0f + 1.0f >= 0.0f) && (y0f + 1.0f <= 31.0f);
      const int ix0 = (int)fminf(fmaxf(x0f, 0.0f), 87.0f);
      const int ix1 = (int)fminf(fmaxf(x0f + 1.0f, 0.0f), 87.0f);
      const int iy0 = (int)fminf(fmaxf(y0f, 0.0f), 31.0f);
      const int iy1 = (int)fminf(fmaxf(y0f + 1.0f, 0.0f), 31.0f);
      const float* ib = imgT + (size_t)b * (HFD * WFD * CD);
      const float f00 = ib[(iy0 * WFD + ix0) * CD + c];
      const float f01 = ib[(iy0 * WFD + ix1) * CD + c];
      const float f10 = ib[(iy1 * WFD + ix0) * CD + c];
      const float f11 = ib[(iy1 * WFD + ix1) * CD + c];
      sval = ((okx0 && oky0) ? (wx0 * wy0) : 0.0f) * f00 +
             ((okx1 && oky0) ? (wx1 * wy0) : 0.0f) * f01 +
             ((okx0 && oky1) ? (wx0 * wy1) : 0.0f) * f10 +
             ((okx1 && oky1) ? (wx1 * wy1) : 0.0f) * f11;
      xval = x[(size_t)n * CD + c];
      if (c == 0) {
        float rn = sqrtf(cx * cx + cy * cy) / 54.0f;
        rn = fminf(fmaxf(rn, 0.0f), 1.0f);
        out[OFF_RN + n]  = rn;
        out[OFF_VAL + n] = validf;
      }
    }
    const int key = (p & 7) << 2;
    sh[p * 256 + (c ^ key)]         = xval;
    sh[p * 256 + ((128 + c) ^ key)] = sval;
  }
  __syncthreads();

  // ---- phase 2: fg MLP (p_fg). thread: p = tid>>2 (point), q = tid&3 ----
  {
    const int p   = tid >> 2;
    const int q   = tid & 3;
    const int n   = base + p;
    const int rb  = p * 256;
    const int key = (p & 7) << 2;
    float acc[16];
#pragma unroll
    for (int i = 0; i < 16; i += 4) {
      const float4 bv = *reinterpret_cast<const float4*>(b1 + q * 16 + i);
      acc[i] = bv.x; acc[i + 1] = bv.y; acc[i + 2] = bv.z; acc[i + 3] = bv.w;
    }
    for (int k = 0; k < CD; k += 4) {
      const float4 xv = *reinterpret_cast<const float4*>(&sh[rb + (k ^ key)]);
      const float* wr = W1 + (size_t)k * HIDD + q * 16;
#pragma unroll
      for (int i = 0; i < 16; i += 4) {
        fma4(acc + i, xv.x, *reinterpret_cast<const float4*>(wr + i));
        fma4(acc + i, xv.y, *reinterpret_cast<const float4*>(wr + HIDD + i));
        fma4(acc + i, xv.z, *reinterpret_cast<const float4*>(wr + 2 * HIDD + i));
        fma4(acc + i, xv.w, *reinterpret_cast<const float4*>(wr + 3 * HIDD + i));
      }
    }
    float s = 0.0f;
#pragma unroll
    for (int i = 0; i < 16; i += 4) {
      const float4 wv = *reinterpret_cast<const float4*>(W2 + q * 16 + i);
      s += fmaxf(acc[i],     0.0f) * wv.x;
      s += fmaxf(acc[i + 1], 0.0f) * wv.y;
      s += fmaxf(acc[i + 2], 0.0f) * wv.z;
      s += fmaxf(acc[i + 3], 0.0f) * wv.w;
    }
    s += __shfl_xor(s, 1);
    s += __shfl_xor(s, 2);
    if (q == 0 && n < N) {
      out[OFF_PFG + n] = 1.0f / (1.0f + expf(-(s + b2[0])));
    }
  }

  // ---- phases 3-5: GEMM2 (cat@We1), GEMM3 (h@We2), epilogue ----
  const int cg   = tid & 7;        // channel group: c0 = cg*16
  const int pg   = tid >> 3;       // point group: p0 = pg*2
  const int c0   = cg * 16;
  const int p0   = pg * 2;
  const int rb0  = p0 * 256;
  const int rb1  = rb0 + 256;
  const int key0 = (p0 & 7) << 2;
  const int key1 = ((p0 + 1) & 7) << 2;

  float h0a[16], h1a[16];
#pragma unroll
  for (int i = 0; i < 16; i += 4) {
    const float4 bv = *reinterpret_cast<const float4*>(be1 + c0 + i);
    h0a[i] = bv.x; h0a[i + 1] = bv.y; h0a[i + 2] = bv.z; h0a[i + 3] = bv.w;
    h1a[i] = bv.x; h1a[i + 1] = bv.y; h1a[i + 2] = bv.z; h1a[i + 3] = bv.w;
  }
#pragma unroll 4
  for (int k = 0; k < 2 * CD; ++k) {
    const float a0  = sh[rb0 + (k ^ key0)];
    const float a1  = sh[rb1 + (k ^ key1)];
    const float* wr = We1 + (size_t)k * CD + c0;
#pragma unroll
    for (int i = 0; i < 16; i += 4) {
      const float4 w = *reinterpret_cast<const float4*>(wr + i);
      fma4(h0a + i, a0, w);
      fma4(h1a + i, a1, w);
    }
  }
#pragma unroll
  for (int i = 0; i < 16; ++i) {
    h0a[i] = fmaxf(h0a[i], 0.0f);
    h1a[i] = fmaxf(h1a[i], 0.0f);
  }
  __syncthreads();   // all GEMM2 reads of the sampled half done
#pragma unroll
  for (int i = 0; i < 16; i += 4) {
    *reinterpret_cast<float4*>(&sh[rb0 + ((CD + c0 + i) ^ key0)]) =
        make_float4(h0a[i], h0a[i + 1], h0a[i + 2], h0a[i + 3]);
    *reinterpret_cast<float4*>(&sh[rb1 + ((CD + c0 + i) ^ key1)]) =
        make_float4(h1a[i], h1a[i + 1], h1a[i + 2], h1a[i + 3]);
  }
  __syncthreads();   // h tile visible

  float d0a[16], d1a[16];
#pragma unroll
  for (int i = 0; i < 16; i += 4) {
    const float4 bv = *reinterpret_cast<const float4*>(be2 + c0 + i);
    d0a[i] = bv.x; d0a[i + 1] = bv.y; d0a[i + 2] = bv.z; d0a[i + 3] = bv.w;
    d1a[i] = bv.x; d1a[i + 1] = bv.y; d1a[i + 2] = bv.z; d1a[i + 3] = bv.w;
  }
#pragma unroll 4
  for (int k = 0; k < CD; ++k) {
    const float a0  = sh[rb0 + ((CD + k) ^ key0)];
    const float a1  = sh[rb1 + ((CD + k) ^ key1)];
    const float* wr = We2 + (size_t)k * CD + c0;
#pragma unroll
    for (int i = 0; i < 16; i += 4) {
      const float4 w = *reinterpret_cast<const float4*>(wr + i);
      fma4(d0a + i, a0, w);
      fma4(d1a + i, a1, w);
    }
  }
  const int n0 = base + p0, n1 = n0 + 1;
  const float vf0 = (n0 < N) ? out[OFF_VAL + n0] : 0.0f;
  const float vf1 = (n1 < N) ? out[OFF_VAL + n1] : 0.0f;
#pragma unroll
  for (int i = 0; i < 16; ++i) { d0a[i] *= vf0; d1a[i] *= vf1; }

  epilogue_point(sh, d0a, p0,     n0, N, c0, cg, lng, lnb, out, OFF_GAIN);
  epilogue_point(sh, d1a, p0 + 1, n1, N, c0, cg, lng, lnb, out, OFF_GAIN);
}

// ---------------------------------------------------------------------------
extern "C" void kernel_launch(void* const* d_in, const int* in_sizes, int n_in,
                              void* d_out, int out_size, void* d_ws, size_t ws_size,
                              hipStream_t stream) {
  const float* x       = (const float*)d_in[0];
  const int*   indices = (const int*)d_in[1];
  const float* voxel   = (const float*)d_in[2];
  const float* pcr     = (const float*)d_in[3];
  const float* aug     = (const float*)d_in[4];
  const float* trans   = (const float*)d_in[5];
  const float* img     = (const float*)d_in[6];
  const float* W1      = (const float*)d_in[7];
  const float* b1      = (const float*)d_in[8];
  const float* W2      = (const float*)d_in[9];
  const float* b2      = (const float*)d_in[10];
  const float* We1     = (const float*)d_in[11];
  const float* be1     = (const float*)d_in[12];
  const float* We2     = (const float*)d_in[13];
  const float* be2     = (const float*)d_in[14];
  const float* lng     = (const float*)d_in[15];
  const float* lnb     = (const float*)d_in[16];
  const int*   img_h   = (const int*)d_in[17];
  const int*   img_w   = (const int*)d_in[18];

  const int N         = in_sizes[0] / CD;
  const int B         = in_sizes[4] / 16;
  const int img_total = in_sizes[6];

  float* auginv = (float*)d_ws;
  float* imgT   = (float*)((char*)d_ws + 1024);

  prep_inv_kernel<<<1, 64, 0, stream>>>(aug, auginv, B);
  transpose_img_kernel<<<(img_total + NTHR - 1) / NTHR, NTHR, 0, stream>>>(
      img, imgT, img_total);
  fused_kernel<<<(N + TILE - 1) / TILE, NTHR, 0, stream>>>(
      x, indices, voxel, pcr, trans, auginv, imgT,
      W1, b1, W2, b2, We1, be1, We2, be2, lng, lnb,
      img_h, img_w, (float*)d_out, N);
}

// Round 2
// 278.135 us; speedup vs baseline: 6.0116x; 6.0116x over previous
//
#include <hip/hip_runtime.h>
#include <math.h>

#define CD  128
#define HFD 32
#define WFD 88

typedef __attribute__((ext_vector_type(4))) float  f4;
typedef __attribute__((ext_vector_type(8))) __bf16 b8;

__device__ __forceinline__ f4 mfma16(b8 a, b8 b, f4 c) {
  return __builtin_amdgcn_mfma_f32_16x16x32_bf16(a, b, c, 0, 0, 0);
}

// ---------------------------------------------------------------------------
// Kernel 1: invert B 4x4 lidar-aug matrices (double-precision Gauss-Jordan)
// ---------------------------------------------------------------------------
__global__ void prep_inv_kernel(const float* __restrict__ aug,
                                float* __restrict__ auginv, int B) {
  int b = threadIdx.x;
  if (b >= B) return;
  double m[4][8];
  for (int i = 0; i < 4; ++i)
    for (int j = 0; j < 4; ++j) {
      m[i][j]     = (double)aug[b * 16 + i * 4 + j];
      m[i][4 + j] = (i == j) ? 1.0 : 0.0;
    }
  for (int col = 0; col < 4; ++col) {
    int piv = col;
    double best = fabs(m[col][col]);
    for (int r = col + 1; r < 4; ++r) {
      double v = fabs(m[r][col]);
      if (v > best) { best = v; piv = r; }
    }
    if (piv != col)
      for (int j = 0; j < 8; ++j) {
        double t = m[col][j]; m[col][j] = m[piv][j]; m[piv][j] = t;
      }
    double f = 1.0 / m[col][col];
    for (int j = 0; j < 8; ++j) m[col][j] *= f;
    for (int r = 0; r < 4; ++r)
      if (r != col) {
        double gg = m[r][col];
        for (int j = 0; j < 8; ++j) m[r][j] -= gg * m[col][j];
      }
  }
  for (int i = 0; i < 4; ++i)
    for (int j = 0; j < 4; ++j)
      auginv[b * 16 + i * 4 + j] = (float)m[i][4 + j];
}

// ---------------------------------------------------------------------------
// Kernel 2: transpose img_feats (B,C,H,W) -> (B,H,W,C) for coalesced gather
// ---------------------------------------------------------------------------
__global__ void transpose_img_kernel(const float* __restrict__ img,
                                     float* __restrict__ imgT, int total) {
  int o = blockIdx.x * blockDim.x + threadIdx.x;
  if (o >= total) return;
  int c   = o & (CD - 1);
  int pos = o >> 7;          // (b*HF + y)*WF + x
  int xw  = pos % WFD;
  int tmp = pos / WFD;       // b*HF + y
  int yh  = tmp & (HFD - 1);
  int b   = tmp >> 5;
  imgT[o] = img[((b * CD + c) * HFD + yh) * WFD + xw];
}

// ---------------------------------------------------------------------------
// Kernel 3: pack W1 (128x64), We1 (256x128), We2 (128x128) into bf16
// A-fragment register order: [mb][kb][lane][j], value = W[k][16*mb+(lane&15)],
// k = 32*kb + 4*(lane>>4) + (j&3) + 16*(j>>2)
// ---------------------------------------------------------------------------
__global__ void pack_weights_kernel(const float* __restrict__ W1,
                                    const float* __restrict__ We1,
                                    const float* __restrict__ We2,
                                    short* __restrict__ W1t,
                                    short* __restrict__ We1t,
                                    short* __restrict__ We2t) {
  int i = blockIdx.x * 256 + threadIdx.x;
  const float* W; short* O; int KB, Nw, idx;
  if (i < 8192)       { W = W1;  O = W1t;  KB = 4; Nw = 64;  idx = i;         }
  else if (i < 40960) { W = We1; O = We1t; KB = 8; Nw = 128; idx = i - 8192;  }
  else if (i < 57344) { W = We2; O = We2t; KB = 4; Nw = 128; idx = i - 40960; }
  else return;
  const int j    = idx & 7;
  const int lane = (idx >> 3) & 63;
  const int blk  = idx >> 9;
  const int kb   = blk % KB, mb = blk / KB;
  const int ch   = 16 * mb + (lane & 15);
  const int k    = 32 * kb + 4 * (lane >> 4) + (j & 3) + 16 * (j >> 2);
  __bf16 h = (__bf16)W[k * Nw + ch];
  short s;
  __builtin_memcpy(&s, &h, 2);
  O[idx] = s;
}

// ---------------------------------------------------------------------------
// Main fused kernel: 256 threads = 4 independent waves, 16 points/wave.
// Lane owns point p = lane&15; all GEMMs operand-swapped (D' = W^T * data^T).
// No LDS, no barriers.
// ---------------------------------------------------------------------------
__global__ __launch_bounds__(256)
void fused_mfma_kernel(const float* __restrict__ x,
                       const int* __restrict__ indices,
                       const float* __restrict__ voxel_size,
                       const float* __restrict__ pc_range,
                       const float* __restrict__ trans,
                       const float* __restrict__ auginv,
                       const float* __restrict__ imgT,
                       const __bf16* __restrict__ W1t,
                       const float* __restrict__ b1,
                       const float* __restrict__ W2,
                       const float* __restrict__ b2,
                       const __bf16* __restrict__ We1t,
                       const float* __restrict__ be1,
                       const __bf16* __restrict__ We2t,
                       const float* __restrict__ be2,
                       const float* __restrict__ lng,
                       const float* __restrict__ lnb,
                       const int* __restrict__ img_h_p,
                       const int* __restrict__ img_w_p,
                       float* __restrict__ out, int N) {
  const int lane = threadIdx.x & 63;
  const int wv   = threadIdx.x >> 6;
  const int g    = lane >> 4;
  const int pl   = lane & 15;
  const int n    = blockIdx.x * 64 + wv * 16 + pl;
  const int nc   = (n < N) ? n : (N - 1);

  const size_t NN       = (size_t)N;
  const size_t OFF_PFG  = NN * CD;
  const size_t OFF_GAIN = OFF_PFG + NN;
  const size_t OFF_RN   = OFF_GAIN + NN;
  const size_t OFF_VAL  = OFF_RN + NN;

  // ---- geometry (per lane, 4x redundant across g-groups; all lane-local) ----
  const float vsx = voxel_size[0] * 8.0f;
  const float vsy = voxel_size[1] * 8.0f;
  const float vsz = voxel_size[2] * 8.0f;
  const float pcx = pc_range[0], pcy = pc_range[1], pcz = pc_range[2];
  const float su  = (float)WFD / (float)(*img_w_p);
  const float sv  = (float)HFD / (float)(*img_h_p);

  const int4 idx = *reinterpret_cast<const int4*>(indices + (size_t)nc * 4);
  const int  b   = idx.x;
  const float cx = (float)idx.w * vsx + pcx + 0.5f * vsx;
  const float cy = (float)idx.z * vsy + pcy + 0.5f * vsy;
  const float cz = (float)idx.y * vsz + pcz + 0.5f * vsz;

  const f4 A0 = *reinterpret_cast<const f4*>(auginv + b * 16 + 0);
  const f4 A1 = *reinterpret_cast<const f4*>(auginv + b * 16 + 4);
  const f4 A2 = *reinterpret_cast<const f4*>(auginv + b * 16 + 8);
  const f4 A3 = *reinterpret_cast<const f4*>(auginv + b * 16 + 12);
  const float h0 = A0[0] * cx + A0[1] * cy + A0[2] * cz + A0[3];
  const float h1 = A1[0] * cx + A1[1] * cy + A1[2] * cz + A1[3];
  const float h2 = A2[0] * cx + A2[1] * cy + A2[2] * cz + A2[3];
  const float h3 = A3[0] * cx + A3[1] * cy + A3[2] * cz + A3[3];
  const f4 T0 = *reinterpret_cast<const f4*>(trans + b * 12 + 0);
  const f4 T1 = *reinterpret_cast<const f4*>(trans + b * 12 + 4);
  const f4 T2 = *reinterpret_cast<const f4*>(trans + b * 12 + 8);
  const float q0    = T0[0] * h0 + T0[1] * h1 + T0[2] * h2 + T0[3] * h3;
  const float q1    = T1[0] * h0 + T1[1] * h1 + T1[2] * h2 + T1[3] * h3;
  const float depth = T2[0] * h0 + T2[1] * h1 + T2[2] * h2 + T2[3] * h3;
  const float safe  = fmaxf(depth, 1e-5f);
  const float u = q0 / safe, v = q1 / safe;
  const float un = 2.0f * (u * su) / 87.0f - 1.0f;
  const float vn = 2.0f * (v * sv) / 31.0f - 1.0f;
  const float vf =
      (depth > 1e-5f && fabsf(un) <= 1.0f && fabsf(vn) <= 1.0f) ? 1.0f : 0.0f;
  float rn = sqrtf(cx * cx + cy * cy) / 54.0f;
  rn = fminf(fmaxf(rn, 0.0f), 1.0f);

  const float xp  = (un + 1.0f) * 0.5f * 87.0f;
  const float yp  = (vn + 1.0f) * 0.5f * 31.0f;
  const float x0f = floorf(xp), y0f = floorf(yp);
  const float wx1 = xp - x0f, wy1 = yp - y0f;
  const float wx0 = 1.0f - wx1, wy0 = 1.0f - wy1;
  const bool okx0 = (x0f >= 0.0f) && (x0f <= 87.0f);
  const bool okx1 = (x0f + 1.0f >= 0.0f) && (x0f + 1.0f <= 87.0f);
  const bool oky0 = (y0f >= 0.0f) && (y0f <= 31.0f);
  const bool oky1 = (y0f + 1.0f >= 0.0f) && (y0f + 1.0f <= 31.0f);
  const int ix0 = (int)fminf(fmaxf(x0f, 0.0f), 87.0f);
  const int ix1 = (int)fminf(fmaxf(x0f + 1.0f, 0.0f), 87.0f);
  const int iy0 = (int)fminf(fmaxf(y0f, 0.0f), 31.0f);
  const int iy1 = (int)fminf(fmaxf(y0f + 1.0f, 0.0f), 31.0f);
  const float w00 = (okx0 && oky0) ? (wx0 * wy0) : 0.0f;
  const float w01 = (okx1 && oky0) ? (wx1 * wy0) : 0.0f;
  const float w10 = (okx0 && oky1) ? (wx0 * wy1) : 0.0f;
  const float w11 = (okx1 && oky1) ? (wx1 * wy1) : 0.0f;
  const float* ibase = imgT + (size_t)b * (HFD * WFD * CD) + 4 * g;
  const int o00 = (iy0 * WFD + ix0) * CD;
  const int o01 = (iy0 * WFD + ix1) * CD;
  const int o10 = (iy1 * WFD + ix0) * CD;
  const int o11 = (iy1 * WFD + ix1) * CD;

  // ---- x loads: lane's k-slice, kept fp32 for the epilogue ----
  f4 xlo[4], xhi[4];
  const float* xrow = x + (size_t)nc * CD + 4 * g;
#pragma unroll
  for (int kb = 0; kb < 4; ++kb) {
    xlo[kb] = *reinterpret_cast<const f4*>(xrow + 32 * kb);
    xhi[kb] = *reinterpret_cast<const f4*>(xrow + 32 * kb + 16);
  }

  // ---- build cat^T B-fragments in registers ----
  b8 catf[8];
#pragma unroll
  for (int kb = 0; kb < 4; ++kb) {
#pragma unroll
    for (int e = 0; e < 4; ++e) {
      catf[kb][e]     = (__bf16)xlo[kb][e];
      catf[kb][4 + e] = (__bf16)xhi[kb][e];
    }
  }
#pragma unroll
  for (int q = 0; q < 8; ++q) {   // sampled half: kb' = q>>1, half = q&1
    const int off = 32 * (q >> 1) + 16 * (q & 1);
    const f4 f00v = *reinterpret_cast<const f4*>(ibase + o00 + off);
    const f4 f01v = *reinterpret_cast<const f4*>(ibase + o01 + off);
    const f4 f10v = *reinterpret_cast<const f4*>(ibase + o10 + off);
    const f4 f11v = *reinterpret_cast<const f4*>(ibase + o11 + off);
    const f4 sv4  = f00v * w00 + f01v * w01 + f10v * w10 + f11v * w11;
    const int hb  = (q & 1) * 4;
#pragma unroll
    for (int e = 0; e < 4; ++e) catf[4 + (q >> 1)][hb + e] = (__bf16)sv4[e];
  }

  // ---- fg MLP: D_fg = W1^T * x^T  (4 mb-tiles x 4 kb) ----
  float sfg = 0.0f;
  {
    f4 accf[4];
#pragma unroll
    for (int mb = 0; mb < 4; ++mb)
      accf[mb] = *reinterpret_cast<const f4*>(b1 + 16 * mb + 4 * g);
#pragma unroll
    for (int kb = 0; kb < 4; ++kb) {
#pragma unroll
      for (int mb = 0; mb < 4; ++mb) {
        const b8 w = *reinterpret_cast<const b8*>(
            W1t + ((size_t)(mb * 4 + kb) * 64 + lane) * 8);
        accf[mb] = mfma16(w, catf[kb], accf[mb]);
      }
    }
#pragma unroll
    for (int mb = 0; mb < 4; ++mb) {
      const f4 w2v = *reinterpret_cast<const f4*>(W2 + 16 * mb + 4 * g);
#pragma unroll
      for (int e = 0; e < 4; ++e) sfg += fmaxf(accf[mb][e], 0.0f) * w2v[e];
    }
    sfg += __shfl_xor(sfg, 16);
    sfg += __shfl_xor(sfg, 32);
  }

  // ---- GEMM2: h^T = We1^T * cat^T  (8 mb x 8 kb) ----
  f4 acc2[8];
#pragma unroll
  for (int mb = 0; mb < 8; ++mb)
    acc2[mb] = *reinterpret_cast<const f4*>(be1 + 16 * mb + 4 * g);
#pragma unroll
  for (int kb = 0; kb < 8; ++kb) {
#pragma unroll
    for (int mb = 0; mb < 8; ++mb) {
      const b8 w = *reinterpret_cast<const b8*>(
          We1t + ((size_t)(mb * 8 + kb) * 64 + lane) * 8);
      acc2[mb] = mfma16(w, catf[kb], acc2[mb]);
    }
  }

  // ---- relu + in-register repack: h^T D-frags -> GEMM3 B-frags ----
  b8 b3[4];
#pragma unroll
  for (int kb = 0; kb < 4; ++kb) {
#pragma unroll
    for (int e = 0; e < 4; ++e) {
      b3[kb][e]     = (__bf16)fmaxf(acc2[2 * kb][e],     0.0f);
      b3[kb][4 + e] = (__bf16)fmaxf(acc2[2 * kb + 1][e], 0.0f);
    }
  }

  // ---- GEMM3: delta^T = We2^T * h^T  (8 mb x 4 kb) ----
  f4 acc3[8];
#pragma unroll
  for (int mb = 0; mb < 8; ++mb)
    acc3[mb] = *reinterpret_cast<const f4*>(be2 + 16 * mb + 4 * g);
#pragma unroll
  for (int kb = 0; kb < 4; ++kb) {
#pragma unroll
    for (int mb = 0; mb < 8; ++mb) {
      const b8 w = *reinterpret_cast<const b8*>(
          We2t + ((size_t)(mb * 4 + kb) * 64 + lane) * 8);
      acc3[mb] = mfma16(w, b3[kb], acc3[mb]);
    }
  }

  // ---- epilogue: mask, norms, LN (per-point = per-lane column) ----
  f4 xrv[8];
  float sd = 0.0f, sx2 = 0.0f, sr = 0.0f, sr2 = 0.0f;
#pragma unroll
  for (int mb = 0; mb < 8; ++mb) {
    const f4 xv = (mb & 1) ? xhi[mb >> 1] : xlo[mb >> 1];
    const f4 d  = acc3[mb] * vf;
    const f4 r  = xv + d;
    xrv[mb] = r;
#pragma unroll
    for (int e = 0; e < 4; ++e) {
      sd  += d[e] * d[e];
      sx2 += xv[e] * xv[e];
      sr  += r[e];
      sr2 += r[e] * r[e];
    }
  }
  sd  += __shfl_xor(sd, 16);  sd  += __shfl_xor(sd, 32);
  sx2 += __shfl_xor(sx2, 16); sx2 += __shfl_xor(sx2, 32);
  sr  += __shfl_xor(sr, 16);  sr  += __shfl_xor(sr, 32);
  sr2 += __shfl_xor(sr2, 16); sr2 += __shfl_xor(sr2, 32);

  const float mu   = sr * (1.0f / 128.0f);
  const float var  = sr2 * (1.0f / 128.0f) - mu * mu;
  const float rstd = rsqrtf(var + 1e-5f);
  const float gn   = sqrtf(sd) / (sqrtf(sx2) + 1e-6f);
  const float fgain = fminf(fmaxf(1.0f - expf(-gn), 0.0f), 1.0f);

  if (n < N) {
#pragma unroll
    for (int mb = 0; mb < 8; ++mb) {
      const f4 gm = *reinterpret_cast<const f4*>(lng + 16 * mb + 4 * g);
      const f4 bt = *reinterpret_cast<const f4*>(lnb + 16 * mb + 4 * g);
      const f4 o  = (xrv[mb] - mu) * rstd * gm + bt;
      *reinterpret_cast<f4*>(out + (size_t)n * CD + 16 * mb + 4 * g) = o;
    }
    if (g == 0) {
      out[OFF_PFG  + n] = 1.0f / (1.0f + expf(-(sfg + b2[0])));
      out[OFF_GAIN + n] = fgain;
      out[OFF_RN   + n] = rn;
      out[OFF_VAL  + n] = vf;
    }
  }
}

// ---------------------------------------------------------------------------
extern "C" void kernel_launch(void* const* d_in, const int* in_sizes, int n_in,
                              void* d_out, int out_size, void* d_ws, size_t ws_size,
                              hipStream_t stream) {
  const float* x       = (const float*)d_in[0];
  const int*   indices = (const int*)d_in[1];
  const float* voxel   = (const float*)d_in[2];
  const float* pcr     = (const float*)d_in[3];
  const float* aug     = (const float*)d_in[4];
  const float* trans   = (const float*)d_in[5];
  const float* img     = (const float*)d_in[6];
  const float* W1      = (const float*)d_in[7];
  const float* b1      = (const float*)d_in[8];
  const float* W2      = (const float*)d_in[9];
  const float* b2      = (const float*)d_in[10];
  const float* We1     = (const float*)d_in[11];
  const float* be1     = (const float*)d_in[12];
  const float* We2     = (const float*)d_in[13];
  const float* be2     = (const float*)d_in[14];
  const float* lng     = (const float*)d_in[15];
  const float* lnb     = (const float*)d_in[16];
  const int*   img_h   = (const int*)d_in[17];
  const int*   img_w   = (const int*)d_in[18];

  const int N         = in_sizes[0] / CD;
  const int B         = in_sizes[4] / 16;
  const int img_total = in_sizes[6];
  const size_t IMG_BYTES = (size_t)img_total * 4;

  char*  wsb    = (char*)d_ws;
  float* auginv = (float*)wsb;
  float* imgT   = (float*)(wsb + 1024);
  short* W1t    = (short*)(wsb + 1024 + IMG_BYTES);
  short* We1t   = W1t + 8192;
  short* We2t   = We1t + 32768;

  prep_inv_kernel<<<1, 64, 0, stream>>>(aug, auginv, B);
  transpose_img_kernel<<<(img_total + 255) / 256, 256, 0, stream>>>(
      img, imgT, img_total);
  pack_weights_kernel<<<224, 256, 0, stream>>>(W1, We1, We2, W1t, We1t, We2t);
  fused_mfma_kernel<<<(N + 63) / 64, 256, 0, stream>>>(
      x, indices, voxel, pcr, trans, auginv, imgT,
      (const __bf16*)W1t, b1, W2, b2,
      (const __bf16*)We1t, be1,
      (const __bf16*)We2t, be2,
      lng, lnb, img_h, img_w, (float*)d_out, N);
}

// Round 4
// 133.642 us; speedup vs baseline: 12.5113x; 2.0812x over previous
//
#include <hip/hip_runtime.h>
#include <math.h>

#define CD  128
#define HFD 32
#define WFD 88

typedef __attribute__((ext_vector_type(4))) float  f4;
typedef __attribute__((ext_vector_type(8))) __bf16 b8;

__device__ __forceinline__ f4 mfma16(b8 a, b8 b, f4 c) {
  return __builtin_amdgcn_mfma_f32_16x16x32_bf16(a, b, c, 0, 0, 0);
}

// ---------------------------------------------------------------------------
// Kernel 1: invert B 4x4 lidar-aug matrices (double-precision Gauss-Jordan)
// ---------------------------------------------------------------------------
__global__ void prep_inv_kernel(const float* __restrict__ aug,
                                float* __restrict__ auginv, int B) {
  int b = threadIdx.x;
  if (b >= B) return;
  double m[4][8];
  for (int i = 0; i < 4; ++i)
    for (int j = 0; j < 4; ++j) {
      m[i][j]     = (double)aug[b * 16 + i * 4 + j];
      m[i][4 + j] = (i == j) ? 1.0 : 0.0;
    }
  for (int col = 0; col < 4; ++col) {
    int piv = col;
    double best = fabs(m[col][col]);
    for (int r = col + 1; r < 4; ++r) {
      double v = fabs(m[r][col]);
      if (v > best) { best = v; piv = r; }
    }
    if (piv != col)
      for (int j = 0; j < 8; ++j) {
        double t = m[col][j]; m[col][j] = m[piv][j]; m[piv][j] = t;
      }
    double f = 1.0 / m[col][col];
    for (int j = 0; j < 8; ++j) m[col][j] *= f;
    for (int r = 0; r < 4; ++r)
      if (r != col) {
        double gg = m[r][col];
        for (int j = 0; j < 8; ++j) m[r][j] -= gg * m[col][j];
      }
  }
  for (int i = 0; i < 4; ++i)
    for (int j = 0; j < 4; ++j)
      auginv[b * 16 + i * 4 + j] = (float)m[i][4 + j];
}

// ---------------------------------------------------------------------------
// Kernel 2: transpose img_feats (B,C,H,W) -> (B,H,W,C) in bf16
// ---------------------------------------------------------------------------
__global__ void transpose_img_kernel(const float* __restrict__ img,
                                     __bf16* __restrict__ imgT, int total) {
  int o = blockIdx.x * blockDim.x + threadIdx.x;
  if (o >= total) return;
  int c   = o & (CD - 1);
  int pos = o >> 7;          // (b*HF + y)*WF + x
  int xw  = pos % WFD;
  int tmp = pos / WFD;       // b*HF + y
  int yh  = tmp & (HFD - 1);
  int b   = tmp >> 5;
  imgT[o] = (__bf16)img[((b * CD + c) * HFD + yh) * WFD + xw];
}

// ---------------------------------------------------------------------------
// Kernel 3: pack weights into bf16 A-fragment register order.
// W1t/We1t (cat-side GEMMs) use k = 32*kb + 8*(lane>>4) + j  (contig-8 map).
// We2t (h-side GEMM) keeps  k = 32*kb + 4*(lane>>4) + (j&3) + 16*(j>>2)
// (pinned by the in-register acc2->b3 repack).
// ---------------------------------------------------------------------------
__global__ void pack_weights_kernel(const float* __restrict__ W1,
                                    const float* __restrict__ We1,
                                    const float* __restrict__ We2,
                                    short* __restrict__ W1t,
                                    short* __restrict__ We1t,
                                    short* __restrict__ We2t) {
  int i = blockIdx.x * 256 + threadIdx.x;
  const float* W; short* O; int KB, Nw, idx; bool cmap;
  if (i < 8192)       { W = W1;  O = W1t;  KB = 4; Nw = 64;  idx = i;         cmap = true;  }
  else if (i < 40960) { W = We1; O = We1t; KB = 8; Nw = 128; idx = i - 8192;  cmap = true;  }
  else if (i < 57344) { W = We2; O = We2t; KB = 4; Nw = 128; idx = i - 40960; cmap = false; }
  else return;
  const int j    = idx & 7;
  const int lane = (idx >> 3) & 63;
  const int blk  = idx >> 9;
  const int kb   = blk % KB, mb = blk / KB;
  const int ch   = 16 * mb + (lane & 15);
  const int k    = cmap ? (32 * kb + 8 * (lane >> 4) + j)
                        : (32 * kb + 4 * (lane >> 4) + (j & 3) + 16 * (j >> 2));
  __bf16 h = (__bf16)W[k * Nw + ch];
  short s;
  __builtin_memcpy(&s, &h, 2);
  O[idx] = s;
}

// ---------------------------------------------------------------------------
// Per-point geometry + cat^T fragment build (lane g owns k-slice 8g..8g+7
// of each 32-block).
// ---------------------------------------------------------------------------
__device__ __forceinline__ void geo_cat(
    int nc, int g, const float* __restrict__ x,
    const int* __restrict__ indices, const __bf16* __restrict__ imgT,
    const float* __restrict__ auginv, const float* __restrict__ trans,
    float vsx, float vsy, float vsz, float pcx, float pcy, float pcz,
    float su, float sv, b8* catf, float& vf_o, float& rn_o) {
  const int4 idx = *reinterpret_cast<const int4*>(indices + (size_t)nc * 4);
  const int  b   = idx.x;
  const float cx = (float)idx.w * vsx + pcx + 0.5f * vsx;
  const float cy = (float)idx.z * vsy + pcy + 0.5f * vsy;
  const float cz = (float)idx.y * vsz + pcz + 0.5f * vsz;

  const f4 A0 = *reinterpret_cast<const f4*>(auginv + b * 16 + 0);
  const f4 A1 = *reinterpret_cast<const f4*>(auginv + b * 16 + 4);
  const f4 A2 = *reinterpret_cast<const f4*>(auginv + b * 16 + 8);
  const f4 A3 = *reinterpret_cast<const f4*>(auginv + b * 16 + 12);
  const float h0 = A0[0] * cx + A0[1] * cy + A0[2] * cz + A0[3];
  const float h1 = A1[0] * cx + A1[1] * cy + A1[2] * cz + A1[3];
  const float h2 = A2[0] * cx + A2[1] * cy + A2[2] * cz + A2[3];
  const float h3 = A3[0] * cx + A3[1] * cy + A3[2] * cz + A3[3];
  const f4 T0 = *reinterpret_cast<const f4*>(trans + b * 12 + 0);
  const f4 T1 = *reinterpret_cast<const f4*>(trans + b * 12 + 4);
  const f4 T2 = *reinterpret_cast<const f4*>(trans + b * 12 + 8);
  const float q0    = T0[0] * h0 + T0[1] * h1 + T0[2] * h2 + T0[3] * h3;
  const float q1    = T1[0] * h0 + T1[1] * h1 + T1[2] * h2 + T1[3] * h3;
  const float depth = T2[0] * h0 + T2[1] * h1 + T2[2] * h2 + T2[3] * h3;
  const float safe  = fmaxf(depth, 1e-5f);
  const float u = q0 / safe, v = q1 / safe;
  const float un = 2.0f * (u * su) / 87.0f - 1.0f;
  const float vn = 2.0f * (v * sv) / 31.0f - 1.0f;
  vf_o = (depth > 1e-5f && fabsf(un) <= 1.0f && fabsf(vn) <= 1.0f) ? 1.0f : 0.0f;
  float rn = sqrtf(cx * cx + cy * cy) / 54.0f;
  rn_o = fminf(fmaxf(rn, 0.0f), 1.0f);

  const float xp  = (un + 1.0f) * 0.5f * 87.0f;
  const float yp  = (vn + 1.0f) * 0.5f * 31.0f;
  const float x0f = floorf(xp), y0f = floorf(yp);
  const float wx1 = xp - x0f, wy1 = yp - y0f;
  const float wx0 = 1.0f - wx1, wy0 = 1.0f - wy1;
  const bool okx0 = (x0f >= 0.0f) && (x0f <= 87.0f);
  const bool okx1 = (x0f + 1.0f >= 0.0f) && (x0f + 1.0f <= 87.0f);
  const bool oky0 = (y0f >= 0.0f) && (y0f <= 31.0f);
  const bool oky1 = (y0f + 1.0f >= 0.0f) && (y0f + 1.0f <= 31.0f);
  const int ix0 = (int)fminf(fmaxf(x0f, 0.0f), 87.0f);
  const int ix1 = (int)fminf(fmaxf(x0f + 1.0f, 0.0f), 87.0f);
  const int iy0 = (int)fminf(fmaxf(y0f, 0.0f), 31.0f);
  const int iy1 = (int)fminf(fmaxf(y0f + 1.0f, 0.0f), 31.0f);
  const float w00 = (okx0 && oky0) ? (wx0 * wy0) : 0.0f;
  const float w01 = (okx1 && oky0) ? (wx1 * wy0) : 0.0f;
  const float w10 = (okx0 && oky1) ? (wx0 * wy1) : 0.0f;
  const float w11 = (okx1 && oky1) ? (wx1 * wy1) : 0.0f;
  const int o00 = (iy0 * WFD + ix0) * CD;
  const int o01 = (iy0 * WFD + ix1) * CD;
  const int o10 = (iy1 * WFD + ix0) * CD;
  const int o11 = (iy1 * WFD + ix1) * CD;
  const __bf16* ib = imgT + (size_t)b * (HFD * WFD * CD);

  // x half: k = 32kb + 8g + j  -> lane loads 8 contiguous floats
  const float* xr = x + (size_t)nc * CD + 8 * g;
#pragma unroll
  for (int kb = 0; kb < 4; ++kb) {
    const f4 a = *reinterpret_cast<const f4*>(xr + 32 * kb);
    const f4 c = *reinterpret_cast<const f4*>(xr + 32 * kb + 4);
    b8 t;
#pragma unroll
    for (int e = 0; e < 4; ++e) {
      t[e]     = (__bf16)a[e];
      t[4 + e] = (__bf16)c[e];
    }
    catf[kb] = t;
  }
  // sampled half: one 16-B bf16 load per corner per kb
#pragma unroll
  for (int kb = 0; kb < 4; ++kb) {
    const int off = 32 * kb + 8 * g;
    const b8 f00 = *reinterpret_cast<const b8*>(ib + o00 + off);
    const b8 f01 = *reinterpret_cast<const b8*>(ib + o01 + off);
    const b8 f10 = *reinterpret_cast<const b8*>(ib + o10 + off);
    const b8 f11 = *reinterpret_cast<const b8*>(ib + o11 + off);
    b8 t;
#pragma unroll
    for (int e = 0; e < 8; ++e) {
      const float s = w00 * (float)f00[e] + w01 * (float)f01[e] +
                      w10 * (float)f10[e] + w11 * (float)f11[e];
      t[e] = (__bf16)s;
    }
    catf[4 + kb] = t;
  }
}

// ---------------------------------------------------------------------------
// Per-point epilogue: mask, norms, LN; x reloaded from L2.
// ---------------------------------------------------------------------------
__device__ __forceinline__ void epilogue_pt(
    const f4* acc3, float vf, float rn, float sfg, int n, int nc, int g, int N,
    const float* __restrict__ x, const float* __restrict__ lng,
    const float* __restrict__ lnb, const float* __restrict__ b2,
    float* __restrict__ out, size_t OFF_PFG, size_t OFF_GAIN, size_t OFF_RN,
    size_t OFF_VAL) {
  f4 xrv[8];
  float sd = 0.0f, sx2 = 0.0f, sr = 0.0f, sr2 = 0.0f;
#pragma unroll
  for (int mb = 0; mb < 8; ++mb) {
    const f4 xv = *reinterpret_cast<const f4*>(x + (size_t)nc * CD + 16 * mb + 4 * g);
    const f4 d  = acc3[mb] * vf;
    const f4 r  = xv + d;
    xrv[mb] = r;
#pragma unroll
    for (int e = 0; e < 4; ++e) {
      sd  += d[e] * d[e];
      sx2 += xv[e] * xv[e];
      sr  += r[e];
      sr2 += r[e] * r[e];
    }
  }
  sd  += __shfl_xor(sd, 16);  sd  += __shfl_xor(sd, 32);
  sx2 += __shfl_xor(sx2, 16); sx2 += __shfl_xor(sx2, 32);
  sr  += __shfl_xor(sr, 16);  sr  += __shfl_xor(sr, 32);
  sr2 += __shfl_xor(sr2, 16); sr2 += __shfl_xor(sr2, 32);

  const float mu   = sr * (1.0f / 128.0f);
  const float var  = sr2 * (1.0f / 128.0f) - mu * mu;
  const float rstd = rsqrtf(var + 1e-5f);
  const float gn   = sqrtf(sd) / (sqrtf(sx2) + 1e-6f);
  const float fgain = fminf(fmaxf(1.0f - expf(-gn), 0.0f), 1.0f);

  if (n < N) {
#pragma unroll
    for (int mb = 0; mb < 8; ++mb) {
      const f4 gm = *reinterpret_cast<const f4*>(lng + 16 * mb + 4 * g);
      const f4 bt = *reinterpret_cast<const f4*>(lnb + 16 * mb + 4 * g);
      const f4 o  = (xrv[mb] - mu) * rstd * gm + bt;
      *reinterpret_cast<f4*>(out + (size_t)n * CD + 16 * mb + 4 * g) = o;
    }
    if (g == 0) {
      out[OFF_PFG  + n] = 1.0f / (1.0f + expf(-(sfg + b2[0])));
      out[OFF_GAIN + n] = fgain;
      out[OFF_RN   + n] = rn;
      out[OFF_VAL  + n] = vf;
    }
  }
}

// ---------------------------------------------------------------------------
// Main fused kernel: 256 threads = 4 waves; each wave owns 32 points
// (2 groups of 16). Every weight fragment loaded once, used by 2 MFMAs.
// No LDS, no barriers.
// ---------------------------------------------------------------------------
__global__ __launch_bounds__(256)
void fused_mfma_kernel(const float* __restrict__ x,
                       const int* __restrict__ indices,
                       const float* __restrict__ voxel_size,
                       const float* __restrict__ pc_range,
                       const float* __restrict__ trans,
                       const float* __restrict__ auginv,
                       const __bf16* __restrict__ imgT,
                       const __bf16* __restrict__ W1t,
                       const float* __restrict__ b1,
                       const float* __restrict__ W2,
                       const float* __restrict__ b2,
                       const __bf16* __restrict__ We1t,
                       const float* __restrict__ be1,
                       const __bf16* __restrict__ We2t,
                       const float* __restrict__ be2,
                       const float* __restrict__ lng,
                       const float* __restrict__ lnb,
                       const int* __restrict__ img_h_p,
                       const int* __restrict__ img_w_p,
                       float* __restrict__ out, int N) {
  const int lane = threadIdx.x & 63;
  const int wv   = threadIdx.x >> 6;
  const int g    = lane >> 4;
  const int pl   = lane & 15;
  const int n0   = blockIdx.x * 128 + wv * 32 + pl;
  const int n1   = n0 + 16;
  const int nc0  = (n0 < N) ? n0 : (N - 1);
  const int nc1  = (n1 < N) ? n1 : (N - 1);

  const size_t NN       = (size_t)N;
  const size_t OFF_PFG  = NN * CD;
  const size_t OFF_GAIN = OFF_PFG + NN;
  const size_t OFF_RN   = OFF_GAIN + NN;
  const size_t OFF_VAL  = OFF_RN + NN;

  const float vsx = voxel_size[0] * 8.0f;
  const float vsy = voxel_size[1] * 8.0f;
  const float vsz = voxel_size[2] * 8.0f;
  const float pcx = pc_range[0], pcy = pc_range[1], pcz = pc_range[2];
  const float su  = (float)WFD / (float)(*img_w_p);
  const float sv  = (float)HFD / (float)(*img_h_p);

  b8 cat0[8], cat1[8];
  float vf0, rn0, vf1, rn1;
  geo_cat(nc0, g, x, indices, imgT, auginv, trans, vsx, vsy, vsz,
          pcx, pcy, pcz, su, sv, cat0, vf0, rn0);
  geo_cat(nc1, g, x, indices, imgT, auginv, trans, vsx, vsy, vsz,
          pcx, pcy, pcz, su, sv, cat1, vf1, rn1);

  // ---- fg MLP: mb-streamed, acc pair live only ----
  float sfg0 = 0.0f, sfg1 = 0.0f;
#pragma unroll
  for (int mb = 0; mb < 4; ++mb) {
    const f4 bi = *reinterpret_cast<const f4*>(b1 + 16 * mb + 4 * g);
    f4 a0 = bi, a1 = bi;
#pragma unroll
    for (int kb = 0; kb < 4; ++kb) {
      const b8 w = *reinterpret_cast<const b8*>(
          W1t + ((size_t)(mb * 4 + kb) * 64 + lane) * 8);
      a0 = mfma16(w, cat0[kb], a0);
      a1 = mfma16(w, cat1[kb], a1);
    }
    const f4 w2v = *reinterpret_cast<const f4*>(W2 + 16 * mb + 4 * g);
#pragma unroll
    for (int e = 0; e < 4; ++e) {
      sfg0 += fmaxf(a0[e], 0.0f) * w2v[e];
      sfg1 += fmaxf(a1[e], 0.0f) * w2v[e];
    }
  }
  sfg0 += __shfl_xor(sfg0, 16); sfg0 += __shfl_xor(sfg0, 32);
  sfg1 += __shfl_xor(sfg1, 16); sfg1 += __shfl_xor(sfg1, 32);

  // ---- GEMM2 in mb-pairs; pair (2pr,2pr+1) immediately packs to b3[pr] ----
  b8 b30[4], b31[4];
#pragma unroll
  for (int pr = 0; pr < 4; ++pr) {
    const f4 biA = *reinterpret_cast<const f4*>(be1 + 16 * (2 * pr) + 4 * g);
    const f4 biB = *reinterpret_cast<const f4*>(be1 + 16 * (2 * pr + 1) + 4 * g);
    f4 aA0 = biA, aB0 = biB, aA1 = biA, aB1 = biB;
#pragma unroll
    for (int kb = 0; kb < 8; ++kb) {
      const b8 wA = *reinterpret_cast<const b8*>(
          We1t + ((size_t)((2 * pr) * 8 + kb) * 64 + lane) * 8);
      const b8 wB = *reinterpret_cast<const b8*>(
          We1t + ((size_t)((2 * pr + 1) * 8 + kb) * 64 + lane) * 8);
      aA0 = mfma16(wA, cat0[kb], aA0);
      aB0 = mfma16(wB, cat0[kb], aB0);
      aA1 = mfma16(wA, cat1[kb], aA1);
      aB1 = mfma16(wB, cat1[kb], aB1);
    }
    b8 t0, t1;
#pragma unroll
    for (int e = 0; e < 4; ++e) {
      t0[e]     = (__bf16)fmaxf(aA0[e], 0.0f);
      t0[4 + e] = (__bf16)fmaxf(aB0[e], 0.0f);
      t1[e]     = (__bf16)fmaxf(aA1[e], 0.0f);
      t1[4 + e] = (__bf16)fmaxf(aB1[e], 0.0f);
    }
    b30[pr] = t0;
    b31[pr] = t1;
  }

  // ---- GEMM3: delta^T = We2^T * h^T ----
  f4 acc30[8], acc31[8];
#pragma unroll
  for (int mb = 0; mb < 8; ++mb) {
    const f4 bi = *reinterpret_cast<const f4*>(be2 + 16 * mb + 4 * g);
    acc30[mb] = bi;
    acc31[mb] = bi;
  }
#pragma unroll
  for (int kb = 0; kb < 4; ++kb) {
#pragma unroll
    for (int mb = 0; mb < 8; ++mb) {
      const b8 w = *reinterpret_cast<const b8*>(
          We2t + ((size_t)(mb * 4 + kb) * 64 + lane) * 8);
      acc30[mb] = mfma16(w, b30[kb], acc30[mb]);
      acc31[mb] = mfma16(w, b31[kb], acc31[mb]);
    }
  }

  epilogue_pt(acc30, vf0, rn0, sfg0, n0, nc0, g, N, x, lng, lnb, b2, out,
              OFF_PFG, OFF_GAIN, OFF_RN, OFF_VAL);
  epilogue_pt(acc31, vf1, rn1, sfg1, n1, nc1, g, N, x, lng, lnb, b2, out,
              OFF_PFG, OFF_GAIN, OFF_RN, OFF_VAL);
}

// ---------------------------------------------------------------------------
extern "C" void kernel_launch(void* const* d_in, const int* in_sizes, int n_in,
                              void* d_out, int out_size, void* d_ws, size_t ws_size,
                              hipStream_t stream) {
  const float* x       = (const float*)d_in[0];
  const int*   indices = (const int*)d_in[1];
  const float* voxel   = (const float*)d_in[2];
  const float* pcr     = (const float*)d_in[3];
  const float* aug     = (const float*)d_in[4];
  const float* trans   = (const float*)d_in[5];
  const float* img     = (const float*)d_in[6];
  const float* W1      = (const float*)d_in[7];
  const float* b1      = (const float*)d_in[8];
  const float* W2      = (const float*)d_in[9];
  const float* b2      = (const float*)d_in[10];
  const float* We1     = (const float*)d_in[11];
  const float* be1     = (const float*)d_in[12];
  const float* We2     = (const float*)d_in[13];
  const float* be2     = (const float*)d_in[14];
  const float* lng     = (const float*)d_in[15];
  const float* lnb     = (const float*)d_in[16];
  const int*   img_h   = (const int*)d_in[17];
  const int*   img_w   = (const int*)d_in[18];

  const int N         = in_sizes[0] / CD;
  const int B         = in_sizes[4] / 16;
  const int img_total = in_sizes[6];
  const size_t IMG_BYTES = (size_t)img_total * 2;   // bf16 now

  char*   wsb    = (char*)d_ws;
  float*  auginv = (float*)wsb;
  __bf16* imgT   = (__bf16*)(wsb + 1024);
  short*  W1t    = (short*)(wsb + 1024 + IMG_BYTES);
  short*  We1t   = W1t + 8192;
  short*  We2t   = We1t + 32768;

  prep_inv_kernel<<<1, 64, 0, stream>>>(aug, auginv, B);
  transpose_img_kernel<<<(img_total + 255) / 256, 256, 0, stream>>>(
      img, imgT, img_total);
  pack_weights_kernel<<<224, 256, 0, stream>>>(W1, We1, We2, W1t, We1t, We2t);
  fused_mfma_kernel<<<(N + 127) / 128, 256, 0, stream>>>(
      x, indices, voxel, pcr, trans, auginv, imgT,
      (const __bf16*)W1t, b1, W2, b2,
      (const __bf16*)We1t, be1,
      (const __bf16*)We2t, be2,
      lng, lnb, img_h, img_w, (float*)d_out, N);
}

// Round 5
// 120.726 us; speedup vs baseline: 13.8499x; 1.1070x over previous
//
#include <hip/hip_runtime.h>
#include <math.h>

#define CD  128
#define HFD 32
#define WFD 88

typedef __attribute__((ext_vector_type(4))) float  f4;
typedef __attribute__((ext_vector_type(8))) __bf16 b8;

__device__ __forceinline__ f4 mfma16(b8 a, b8 b, f4 c) {
  return __builtin_amdgcn_mfma_f32_16x16x32_bf16(a, b, c, 0, 0, 0);
}

// ---------------------------------------------------------------------------
// Kernel 1: invert B 4x4 lidar-aug matrices (double-precision Gauss-Jordan)
// ---------------------------------------------------------------------------
__global__ void prep_inv_kernel(const float* __restrict__ aug,
                                float* __restrict__ auginv, int B) {
  int b = threadIdx.x;
  if (b >= B) return;
  double m[4][8];
  for (int i = 0; i < 4; ++i)
    for (int j = 0; j < 4; ++j) {
      m[i][j]     = (double)aug[b * 16 + i * 4 + j];
      m[i][4 + j] = (i == j) ? 1.0 : 0.0;
    }
  for (int col = 0; col < 4; ++col) {
    int piv = col;
    double best = fabs(m[col][col]);
    for (int r = col + 1; r < 4; ++r) {
      double v = fabs(m[r][col]);
      if (v > best) { best = v; piv = r; }
    }
    if (piv != col)
      for (int j = 0; j < 8; ++j) {
        double t = m[col][j]; m[col][j] = m[piv][j]; m[piv][j] = t;
      }
    double f = 1.0 / m[col][col];
    for (int j = 0; j < 8; ++j) m[col][j] *= f;
    for (int r = 0; r < 4; ++r)
      if (r != col) {
        double gg = m[r][col];
        for (int j = 0; j < 8; ++j) m[r][j] -= gg * m[col][j];
      }
  }
  for (int i = 0; i < 4; ++i)
    for (int j = 0; j < 4; ++j)
      auginv[b * 16 + i * 4 + j] = (float)m[i][4 + j];
}

// ---------------------------------------------------------------------------
// Kernel 2: transpose img_feats (B,C,H,W) -> (B,H,W,C) in bf16
// ---------------------------------------------------------------------------
__global__ void transpose_img_kernel(const float* __restrict__ img,
                                     __bf16* __restrict__ imgT, int total) {
  int o = blockIdx.x * blockDim.x + threadIdx.x;
  if (o >= total) return;
  int c   = o & (CD - 1);
  int pos = o >> 7;          // (b*HF + y)*WF + x
  int xw  = pos % WFD;
  int tmp = pos / WFD;       // b*HF + y
  int yh  = tmp & (HFD - 1);
  int b   = tmp >> 5;
  imgT[o] = (__bf16)img[((b * CD + c) * HFD + yh) * WFD + xw];
}

// ---------------------------------------------------------------------------
// Kernel 3: pack weights into bf16 A-fragment register order.
// Fragment f occupies shorts [f*512, (f+1)*512): lane l holds 8 shorts at
// f*512 + l*8. W1t = frags 0..15, We1t = frags 16..79, We2t = frags 80..111.
// W1t/We1t (cat-side) use k = 32*kb + 8*(lane>>4) + j (contig-8 map).
// We2t (h-side) keeps   k = 32*kb + 4*(lane>>4) + (j&3) + 16*(j>>2)
// (pinned by the in-register acc2->b3 repack).
// ---------------------------------------------------------------------------
__global__ void pack_weights_kernel(const float* __restrict__ W1,
                                    const float* __restrict__ We1,
                                    const float* __restrict__ We2,
                                    short* __restrict__ W1t,
                                    short* __restrict__ We1t,
                                    short* __restrict__ We2t) {
  int i = blockIdx.x * 256 + threadIdx.x;
  const float* W; short* O; int KB, Nw, idx; bool cmap;
  if (i < 8192)       { W = W1;  O = W1t;  KB = 4; Nw = 64;  idx = i;         cmap = true;  }
  else if (i < 40960) { W = We1; O = We1t; KB = 8; Nw = 128; idx = i - 8192;  cmap = true;  }
  else if (i < 57344) { W = We2; O = We2t; KB = 4; Nw = 128; idx = i - 40960; cmap = false; }
  else return;
  const int j    = idx & 7;
  const int lane = (idx >> 3) & 63;
  const int blk  = idx >> 9;
  const int kb   = blk % KB, mb = blk / KB;
  const int ch   = 16 * mb + (lane & 15);
  const int k    = cmap ? (32 * kb + 8 * (lane >> 4) + j)
                        : (32 * kb + 4 * (lane >> 4) + (j & 3) + 16 * (j >> 2));
  __bf16 h = (__bf16)W[k * Nw + ch];
  short s;
  __builtin_memcpy(&s, &h, 2);
  O[idx] = s;
}

// ---------------------------------------------------------------------------
// Per-point geometry + cat^T fragment build (lane g owns k-slice 8g..8g+7
// of each 32-block).
// ---------------------------------------------------------------------------
__device__ __forceinline__ void geo_cat(
    int nc, int g, const float* __restrict__ x,
    const int* __restrict__ indices, const __bf16* __restrict__ imgT,
    const float* __restrict__ auginv, const float* __restrict__ trans,
    float vsx, float vsy, float vsz, float pcx, float pcy, float pcz,
    float su, float sv, b8* catf, float& vf_o, float& rn_o) {
  const int4 idx = *reinterpret_cast<const int4*>(indices + (size_t)nc * 4);
  const int  b   = idx.x;
  const float cx = (float)idx.w * vsx + pcx + 0.5f * vsx;
  const float cy = (float)idx.z * vsy + pcy + 0.5f * vsy;
  const float cz = (float)idx.y * vsz + pcz + 0.5f * vsz;

  const f4 A0 = *reinterpret_cast<const f4*>(auginv + b * 16 + 0);
  const f4 A1 = *reinterpret_cast<const f4*>(auginv + b * 16 + 4);
  const f4 A2 = *reinterpret_cast<const f4*>(auginv + b * 16 + 8);
  const f4 A3 = *reinterpret_cast<const f4*>(auginv + b * 16 + 12);
  const float h0 = A0[0] * cx + A0[1] * cy + A0[2] * cz + A0[3];
  const float h1 = A1[0] * cx + A1[1] * cy + A1[2] * cz + A1[3];
  const float h2 = A2[0] * cx + A2[1] * cy + A2[2] * cz + A2[3];
  const float h3 = A3[0] * cx + A3[1] * cy + A3[2] * cz + A3[3];
  const f4 T0 = *reinterpret_cast<const f4*>(trans + b * 12 + 0);
  const f4 T1 = *reinterpret_cast<const f4*>(trans + b * 12 + 4);
  const f4 T2 = *reinterpret_cast<const f4*>(trans + b * 12 + 8);
  const float q0    = T0[0] * h0 + T0[1] * h1 + T0[2] * h2 + T0[3] * h3;
  const float q1    = T1[0] * h0 + T1[1] * h1 + T1[2] * h2 + T1[3] * h3;
  const float depth = T2[0] * h0 + T2[1] * h1 + T2[2] * h2 + T2[3] * h3;
  const float safe  = fmaxf(depth, 1e-5f);
  const float u = q0 / safe, v = q1 / safe;
  const float un = 2.0f * (u * su) / 87.0f - 1.0f;
  const float vn = 2.0f * (v * sv) / 31.0f - 1.0f;
  vf_o = (depth > 1e-5f && fabsf(un) <= 1.0f && fabsf(vn) <= 1.0f) ? 1.0f : 0.0f;
  float rn = sqrtf(cx * cx + cy * cy) / 54.0f;
  rn_o = fminf(fmaxf(rn, 0.0f), 1.0f);

  const float xp  = (un + 1.0f) * 0.5f * 87.0f;
  const float yp  = (vn + 1.0f) * 0.5f * 31.0f;
  const float x0f = floorf(xp), y0f = floorf(yp);
  const float wx1 = xp - x0f, wy1 = yp - y0f;
  const float wx0 = 1.0f - wx1, wy0 = 1.0f - wy1;
  const bool okx0 = (x0f >= 0.0f) && (x0f <= 87.0f);
  const bool okx1 = (x0f + 1.0f >= 0.0f) && (x0f + 1.0f <= 87.0f);
  const bool oky0 = (y0f >= 0.0f) && (y0f <= 31.0f);
  const bool oky1 = (y0f + 1.0f >= 0.0f) && (y0f + 1.0f <= 31.0f);
  const int ix0 = (int)fminf(fmaxf(x0f, 0.0f), 87.0f);
  const int ix1 = (int)fminf(fmaxf(x0f + 1.0f, 0.0f), 87.0f);
  const int iy0 = (int)fminf(fmaxf(y0f, 0.0f), 31.0f);
  const int iy1 = (int)fminf(fmaxf(y0f + 1.0f, 0.0f), 31.0f);
  const float w00 = (okx0 && oky0) ? (wx0 * wy0) : 0.0f;
  const float w01 = (okx1 && oky0) ? (wx1 * wy0) : 0.0f;
  const float w10 = (okx0 && oky1) ? (wx0 * wy1) : 0.0f;
  const float w11 = (okx1 && oky1) ? (wx1 * wy1) : 0.0f;
  const int o00 = (iy0 * WFD + ix0) * CD;
  const int o01 = (iy0 * WFD + ix1) * CD;
  const int o10 = (iy1 * WFD + ix0) * CD;
  const int o11 = (iy1 * WFD + ix1) * CD;
  const __bf16* ib = imgT + (size_t)b * (HFD * WFD * CD);

  // x half: k = 32kb + 8g + j  -> lane loads 8 contiguous floats
  const float* xr = x + (size_t)nc * CD + 8 * g;
#pragma unroll
  for (int kb = 0; kb < 4; ++kb) {
    const f4 a = *reinterpret_cast<const f4*>(xr + 32 * kb);
    const f4 c = *reinterpret_cast<const f4*>(xr + 32 * kb + 4);
    b8 t;
#pragma unroll
    for (int e = 0; e < 4; ++e) {
      t[e]     = (__bf16)a[e];
      t[4 + e] = (__bf16)c[e];
    }
    catf[kb] = t;
  }
  // sampled half: one 16-B bf16 load per corner per kb
#pragma unroll
  for (int kb = 0; kb < 4; ++kb) {
    const int off = 32 * kb + 8 * g;
    const b8 f00 = *reinterpret_cast<const b8*>(ib + o00 + off);
    const b8 f01 = *reinterpret_cast<const b8*>(ib + o01 + off);
    const b8 f10 = *reinterpret_cast<const b8*>(ib + o10 + off);
    const b8 f11 = *reinterpret_cast<const b8*>(ib + o11 + off);
    b8 t;
#pragma unroll
    for (int e = 0; e < 8; ++e) {
      const float s = w00 * (float)f00[e] + w01 * (float)f01[e] +
                      w10 * (float)f10[e] + w11 * (float)f11[e];
      t[e] = (__bf16)s;
    }
    catf[4 + kb] = t;
  }
}

// ---------------------------------------------------------------------------
// Per-point epilogue: mask, norms, LN; x reloaded (L2-hot).
// ---------------------------------------------------------------------------
__device__ __forceinline__ void epilogue_pt(
    const f4* acc3, float vf, float rn, float sfg, int n, int nc, int g, int N,
    const float* __restrict__ x, const float* __restrict__ lng,
    const float* __restrict__ lnb, const float* __restrict__ b2,
    float* __restrict__ out, size_t OFF_PFG, size_t OFF_GAIN, size_t OFF_RN,
    size_t OFF_VAL) {
  f4 xrv[8];
  float sd = 0.0f, sx2 = 0.0f, sr = 0.0f, sr2 = 0.0f;
#pragma unroll
  for (int mb = 0; mb < 8; ++mb) {
    const f4 xv = *reinterpret_cast<const f4*>(x + (size_t)nc * CD + 16 * mb + 4 * g);
    const f4 d  = acc3[mb] * vf;
    const f4 r  = xv + d;
    xrv[mb] = r;
#pragma unroll
    for (int e = 0; e < 4; ++e) {
      sd  += d[e] * d[e];
      sx2 += xv[e] * xv[e];
      sr  += r[e];
      sr2 += r[e] * r[e];
    }
  }
  sd  += __shfl_xor(sd, 16);  sd  += __shfl_xor(sd, 32);
  sx2 += __shfl_xor(sx2, 16); sx2 += __shfl_xor(sx2, 32);
  sr  += __shfl_xor(sr, 16);  sr  += __shfl_xor(sr, 32);
  sr2 += __shfl_xor(sr2, 16); sr2 += __shfl_xor(sr2, 32);

  const float mu   = sr * (1.0f / 128.0f);
  const float var  = sr2 * (1.0f / 128.0f) - mu * mu;
  const float rstd = rsqrtf(var + 1e-5f);
  const float gn   = sqrtf(sd) / (sqrtf(sx2) + 1e-6f);
  const float fgain = fminf(fmaxf(1.0f - expf(-gn), 0.0f), 1.0f);

  if (n < N) {
#pragma unroll
    for (int mb = 0; mb < 8; ++mb) {
      const f4 gm = *reinterpret_cast<const f4*>(lng + 16 * mb + 4 * g);
      const f4 bt = *reinterpret_cast<const f4*>(lnb + 16 * mb + 4 * g);
      const f4 o  = (xrv[mb] - mu) * rstd * gm + bt;
      *reinterpret_cast<f4*>(out + (size_t)n * CD + 16 * mb + 4 * g) = o;
    }
    if (g == 0) {
      out[OFF_PFG  + n] = 1.0f / (1.0f + expf(-(sfg + b2[0])));
      out[OFF_GAIN + n] = fgain;
      out[OFF_RN   + n] = rn;
      out[OFF_VAL  + n] = vf;
    }
  }
}

// ---------------------------------------------------------------------------
// Main fused kernel: 768 threads = 12 waves; 16 points/wave (192 pts/block).
// All packed weights (112 KB) staged once per block into LDS; every MFMA
// A-fragment is then a conflict-free ds_read_b128.
// ---------------------------------------------------------------------------
__global__ __launch_bounds__(768)
void fused_mfma_kernel(const float* __restrict__ x,
                       const int* __restrict__ indices,
                       const float* __restrict__ voxel_size,
                       const float* __restrict__ pc_range,
                       const float* __restrict__ trans,
                       const float* __restrict__ auginv,
                       const __bf16* __restrict__ imgT,
                       const short* __restrict__ wsrc,   // W1t|We1t|We2t packed
                       const float* __restrict__ b1,
                       const float* __restrict__ W2,
                       const float* __restrict__ b2,
                       const float* __restrict__ be1,
                       const float* __restrict__ be2,
                       const float* __restrict__ lng,
                       const float* __restrict__ lnb,
                       const int* __restrict__ img_h_p,
                       const int* __restrict__ img_w_p,
                       float* __restrict__ out, int N) {
  __shared__ __align__(16) short wlds[57344];   // 112 KB: 112 fragments
  const int tid  = threadIdx.x;
  const int lane = tid & 63;
  const int wv   = tid >> 6;        // 0..11
  const int g    = lane >> 4;
  const int pl   = lane & 15;
  const int n    = blockIdx.x * 192 + wv * 16 + pl;
  const int nc   = (n < N) ? n : (N - 1);

  const size_t NN       = (size_t)N;
  const size_t OFF_PFG  = NN * CD;
  const size_t OFF_GAIN = OFF_PFG + NN;
  const size_t OFF_RN   = OFF_GAIN + NN;
  const size_t OFF_VAL  = OFF_RN + NN;

  // ---- stage all weights to LDS: 7168 x 16B, 10 chunks/thread (wrapped) ----
  {
    const uint4* ws4 = reinterpret_cast<const uint4*>(wsrc);
    uint4* wl4       = reinterpret_cast<uint4*>(wlds);
    uint4 tmp[10];
#pragma unroll
    for (int i = 0; i < 10; ++i) {
      int c = tid + i * 768;
      if (c >= 7168) c -= 7168;
      tmp[i] = ws4[c];
    }
#pragma unroll
    for (int i = 0; i < 10; ++i) {
      int c = tid + i * 768;
      if (c >= 7168) c -= 7168;
      wl4[c] = tmp[i];
    }
  }

  const float vsx = voxel_size[0] * 8.0f;
  const float vsy = voxel_size[1] * 8.0f;
  const float vsz = voxel_size[2] * 8.0f;
  const float pcx = pc_range[0], pcy = pc_range[1], pcz = pc_range[2];
  const float su  = (float)WFD / (float)(*img_w_p);
  const float sv  = (float)HFD / (float)(*img_h_p);

  b8 cat[8];
  float vf, rn;
  geo_cat(nc, g, x, indices, imgT, auginv, trans, vsx, vsy, vsz,
          pcx, pcy, pcz, su, sv, cat, vf, rn);

  __syncthreads();   // weights visible

  const short* wb = wlds + lane * 8;   // lane-local base; frag f at +f*512

  // ---- fg MLP: frags 0..15 ----
  float sfg = 0.0f;
#pragma unroll
  for (int mb = 0; mb < 4; ++mb) {
    f4 a = *reinterpret_cast<const f4*>(b1 + 16 * mb + 4 * g);
#pragma unroll
    for (int kb = 0; kb < 4; ++kb) {
      const b8 w = *reinterpret_cast<const b8*>(wb + (mb * 4 + kb) * 512);
      a = mfma16(w, cat[kb], a);
    }
    const f4 w2v = *reinterpret_cast<const f4*>(W2 + 16 * mb + 4 * g);
#pragma unroll
    for (int e = 0; e < 4; ++e) sfg += fmaxf(a[e], 0.0f) * w2v[e];
  }
  sfg += __shfl_xor(sfg, 16);
  sfg += __shfl_xor(sfg, 32);

  // ---- GEMM2 in mb-pairs (frags 16..79); pair packs to b3[pr] ----
  b8 b3[4];
#pragma unroll
  for (int pr = 0; pr < 4; ++pr) {
    f4 aA = *reinterpret_cast<const f4*>(be1 + 16 * (2 * pr) + 4 * g);
    f4 aB = *reinterpret_cast<const f4*>(be1 + 16 * (2 * pr + 1) + 4 * g);
#pragma unroll
    for (int kb = 0; kb < 8; ++kb) {
      const b8 wA = *reinterpret_cast<const b8*>(wb + (16 + (2 * pr) * 8 + kb) * 512);
      const b8 wB = *reinterpret_cast<const b8*>(wb + (16 + (2 * pr + 1) * 8 + kb) * 512);
      aA = mfma16(wA, cat[kb], aA);
      aB = mfma16(wB, cat[kb], aB);
    }
    b8 t;
#pragma unroll
    for (int e = 0; e < 4; ++e) {
      t[e]     = (__bf16)fmaxf(aA[e], 0.0f);
      t[4 + e] = (__bf16)fmaxf(aB[e], 0.0f);
    }
    b3[pr] = t;
  }

  // ---- GEMM3: delta^T = We2^T * h^T (frags 80..111) ----
  f4 acc3[8];
#pragma unroll
  for (int mb = 0; mb < 8; ++mb)
    acc3[mb] = *reinterpret_cast<const f4*>(be2 + 16 * mb + 4 * g);
#pragma unroll
  for (int kb = 0; kb < 4; ++kb) {
#pragma unroll
    for (int mb = 0; mb < 8; ++mb) {
      const b8 w = *reinterpret_cast<const b8*>(wb + (80 + mb * 4 + kb) * 512);
      acc3[mb] = mfma16(w, b3[kb], acc3[mb]);
    }
  }

  epilogue_pt(acc3, vf, rn, sfg, n, nc, g, N, x, lng, lnb, b2, out,
              OFF_PFG, OFF_GAIN, OFF_RN, OFF_VAL);
}

// ---------------------------------------------------------------------------
extern "C" void kernel_launch(void* const* d_in, const int* in_sizes, int n_in,
                              void* d_out, int out_size, void* d_ws, size_t ws_size,
                              hipStream_t stream) {
  const float* x       = (const float*)d_in[0];
  const int*   indices = (const int*)d_in[1];
  const float* voxel   = (const float*)d_in[2];
  const float* pcr     = (const float*)d_in[3];
  const float* aug     = (const float*)d_in[4];
  const float* trans   = (const float*)d_in[5];
  const float* img     = (const float*)d_in[6];
  const float* W1      = (const float*)d_in[7];
  const float* b1      = (const float*)d_in[8];
  const float* W2      = (const float*)d_in[9];
  const float* b2      = (const float*)d_in[10];
  const float* We1     = (const float*)d_in[11];
  const float* be1     = (const float*)d_in[12];
  const float* We2     = (const float*)d_in[13];
  const float* be2     = (const float*)d_in[14];
  const float* lng     = (const float*)d_in[15];
  const float* lnb     = (const float*)d_in[16];
  const int*   img_h   = (const int*)d_in[17];
  const int*   img_w   = (const int*)d_in[18];

  const int N         = in_sizes[0] / CD;
  const int B         = in_sizes[4] / 16;
  const int img_total = in_sizes[6];
  const size_t IMG_BYTES = (size_t)img_total * 2;   // bf16

  char*   wsb    = (char*)d_ws;
  float*  auginv = (float*)wsb;
  __bf16* imgT   = (__bf16*)(wsb + 1024);
  short*  W1t    = (short*)(wsb + 1024 + IMG_BYTES);   // frags 0..15
  short*  We1t   = W1t + 8192;                         // frags 16..79
  short*  We2t   = We1t + 32768;                       // frags 80..111

  prep_inv_kernel<<<1, 64, 0, stream>>>(aug, auginv, B);
  transpose_img_kernel<<<(img_total + 255) / 256, 256, 0, stream>>>(
      img, imgT, img_total);
  pack_weights_kernel<<<224, 256, 0, stream>>>(W1, We1, We2, W1t, We1t, We2t);
  fused_mfma_kernel<<<(N + 191) / 192, 768, 0, stream>>>(
      x, indices, voxel, pcr, trans, auginv, imgT,
      W1t, b1, W2, b2, be1, be2,
      lng, lnb, img_h, img_w, (float*)d_out, N);
}